// Round 17
// baseline (1979.315 us; speedup 1.0000x reference)
//
#include <hip/hip_runtime.h>

#define LROW    2904
#define PERIOD  24
#define CYC     121          // cycles; odd -> median = 0-indexed rank 60
#define NF      207
#define KF      208          // padded f-width (832B rows, 64B-aligned)
#define NB      64
#define NROWS   13248
#define NSLOT   61           // 121 keys packed 2/u32 (+1 sentinel halfword)
#define NT      256
#define LTILE   24
#define NLT     121
#define K2GRID  (NB * NLT)   // 7744
#define K2CHUNK (K2GRID / 8)
#define R13     (1.f / 13.f)

typedef unsigned short us2 __attribute__((ext_vector_type(2)));

__device__ __forceinline__ int clampi(int i) {
    return i < 0 ? 0 : (i >= LROW ? LROW - 1 : i);
}
__device__ __forceinline__ unsigned quantk(float d) {
    int ki = (int)fmaf(d, 4096.f, 32768.f);
    ki = ki < 0 ? 0 : (ki > 65535 ? 65535 : ki);
    return (unsigned)ki;
}
__device__ __forceinline__ float dqmid(unsigned k) {
    return ((float)(int)k - 32767.5f) * (1.f / 4096.f);
}

__device__ __forceinline__ unsigned selN(const unsigned (&K)[NSLOT], int thr) {
    unsigned T = 0;
    const us2 one2 = __builtin_bit_cast(us2, 0x00010001u);
    for (int bit = 15; bit >= 0; --bit) {
        unsigned Tp = T | (1u << bit);
        unsigned tm32 = (Tp - 1u) | ((Tp - 1u) << 16);
        us2 tm2 = __builtin_bit_cast(us2, tm32);
        us2 acc = __builtin_bit_cast(us2, 0u);
        #pragma unroll
        for (int s = 0; s < NSLOT; ++s) {
            us2 kv = __builtin_bit_cast(us2, K[s]);
            us2 dd = __builtin_elementwise_sub_sat(kv, tm2);
            us2 mm = __builtin_elementwise_min(dd, one2);
            acc = acc + mm;
        }
        unsigned a = __builtin_bit_cast(unsigned, acc);
        int cnt = (int)(a & 0xFFFFu) + (int)(a >> 16);
        if (cnt >= thr) T = Tp;
    }
    return T;
}

// ===== K0: keys (R16) — DIAGNOSTIC rep=16 ==================================
__global__ __launch_bounds__(256) void k_keys(const float* __restrict__ x,
                                              unsigned* __restrict__ keys,
                                              int rep) {
    __shared__ float T[62 * NF];
    const int b  = blockIdx.x;
    const int cp = blockIdx.y;
    const int fl = threadIdx.x;
    const int fe = fl < NF ? fl : NF - 1;
    const int l0 = cp * 48;
    const float* xb = x + (size_t)b * (LROW * NF);
    unsigned* kb = keys + ((size_t)b * PERIOD * NSLOT + cp) * KF + fl;

    #pragma unroll 1
    for (int q = 0; q < rep; ++q) {
        if (cp != 0 && cp != 60) {
            const float2* s2 = (const float2*)(xb + (size_t)(l0 - 8) * NF);
            float2* t2 = (float2*)T;
            for (int i = fl; i < 62 * NF / 2; i += NT) t2[i] = s2[i];
        } else {
            for (int i = fl; i < 62 * NF; i += NT) {
                int lr = i / NF, ff = i - lr * NF;
                T[i] = xb[(size_t)clampi(l0 - 8 + lr) * NF + ff];
            }
        }
        __syncthreads();

        float r[13];
        #pragma unroll
        for (int i = 0; i < 13; ++i) r[i] = T[(i + 1) * NF + fe];
        float sum = ((r[0]+r[1])+(r[2]+r[3]))+((r[4]+r[5])+(r[6]+r[7]))
                  + ((r[8]+r[9])+(r[10]+r[11])) + r[12];

        if (cp < 60) {
            unsigned pend[PERIOD];
            #pragma unroll
            for (int j = 0; j < 48; ++j) {
                float xn = T[(j + 14) * NF + fe];
                sum += xn - r[0];
                unsigned k = quantk(r[7] - sum * R13);
                if (j < 24) pend[j] = k;
                else if (fl < KF)
                    kb[(size_t)(j - 24) * (NSLOT * KF)] = pend[j - 24] | (k << 16);
                #pragma unroll
                for (int i = 0; i < 12; ++i) r[i] = r[i + 1];
                r[12] = xn;
            }
        } else {
            #pragma unroll
            for (int j = 0; j < 24; ++j) {
                float xn = T[(j + 14) * NF + fe];
                sum += xn - r[0];
                unsigned k = quantk(r[7] - sum * R13);
                if (fl < KF)
                    kb[(size_t)j * (NSLOT * KF)] = k | 0xFFFF0000u;
                #pragma unroll
                for (int i = 0; i < 12; ++i) r[i] = r[i + 1];
                r[12] = xn;
            }
        }
        __syncthreads();                       // protect LDS restage
        asm volatile("" ::: "memory");         // force reload next rep
    }
}

// ===== K1: iter-0 medians — DIAGNOSTIC rep=16 ==============================
__global__ __launch_bounds__(256) void k_med0(const unsigned* __restrict__ keys,
                                              unsigned short* __restrict__ m0key,
                                              int rep) {
    const int d  = blockIdx.x;                      // 1536 = 8*192, bijective
    const int bp = (d & 7) * 192 + (d >> 3);
    const int fl = threadIdx.x;
    const int fx = fl < KF ? fl : KF - 1;
    #pragma unroll 1
    for (int q = 0; q < rep; ++q) {
        unsigned K[NSLOT];
        const unsigned* kp = keys + (size_t)bp * NSLOT * KF + fx;
        #pragma unroll
        for (int s = 0; s < NSLOT; ++s) K[s] = kp[(size_t)s * KF];
        unsigned T = selN(K, 62);
        if (fl < KF) m0key[(size_t)bp * KF + fl] = (unsigned short)T;
        asm volatile("" ::: "memory");
    }
}

// ===== K2: iter-1 edge resolve via O(1) replacement rule (R16, rep=1) ======
__global__ __launch_bounds__(256) void k_edge2(const unsigned* __restrict__ keys,
                                               const unsigned short* __restrict__ m0key,
                                               float* __restrict__ medBedge) {
    const int d  = blockIdx.x;                      // 768 = 8*96, bijective
    const int be = (d & 7) * 96 + (d >> 3);
    const int b = be / 12, e = be - 12 * b;
    const int p = (e < 6) ? e : e + 12;
    const int fl = threadIdx.x;
    const int fx = fl < KF ? fl : KF - 1;

    float m0[PERIOD];
    #pragma unroll
    for (int q = 0; q < PERIOD; ++q)
        m0[q] = dqmid(m0key[(size_t)(b * PERIOD + q) * KF + fx]);

    float wph = 0.f, we = 0.f;
    #pragma unroll
    for (int ee = 0; ee < 12; ++ee) if (ee == e) {
        const int pp = (ee < 6) ? ee : ee + 12;
        #pragma unroll
        for (int t = 0; t < 13; ++t) wph += m0[(pp + 18 + t) % 24];
        #pragma unroll
        for (int t = -6; t <= 6; ++t) {
            int aa = pp + t; if (aa < 0) aa = 0; if (aa > 23) aa = 23;
            we += m0[aa];
        }
    }

    unsigned K[NSLOT];
    const unsigned* kp = keys + (size_t)(b * PERIOD + p) * NSLOT * KF + fx;
    #pragma unroll
    for (int s = 0; s < NSLOT; ++s) K[s] = kp[(size_t)s * KF];

    unsigned m = (unsigned)m0key[(size_t)(b * PERIOD + p) * KF + fx];
    unsigned xk = ((p < 6) ? K[0] : K[60]) & 0xFFFFu;
    unsigned y = quantk(dqmid(xk) + (we - wph) * R13);

    int thr = (y > m) ? 61 : 63;
    unsigned v = selN(K, thr);
    bool up = (y > m) && (xk <= m);
    bool dn = (y < m) && (xk >= m);
    unsigned nm = up ? (y < v ? y : v) : (dn ? (y > v ? y : v) : m);
    if (fl < KF)
        medBedge[(size_t)(b * 12 + e) * KF + fl] = dqmid(nm) + wph * R13;
}

// ===== K3: outputs (R16, rep=1) ============================================
__global__ __launch_bounds__(NT, 5) void stl_outputs(const float* __restrict__ x,
                                                     const unsigned short* __restrict__ m0key,
                                                     const float* __restrict__ medBedge,
                                                     float* __restrict__ out) {
    __shared__ float T[(LTILE + 12) * NF];

    const int d   = blockIdx.x;
    const int blk = (d & 7) * K2CHUNK + (d >> 3);
    const int b  = blk / NLT;
    const int kk = blk - b * NLT;
    const int l0 = kk * LTILE;
    const int t  = threadIdx.x;
    const float* xb = x + (size_t)b * (LROW * NF);

    if (kk != 0 && kk != NLT - 1) {
        const float2* s2 = (const float2*)(xb + (size_t)(l0 - 6) * NF);
        float2* t2 = (float2*)T;
        for (int i = t; i < (LTILE + 12) * NF / 2; i += NT) t2[i] = s2[i];
    } else {
        for (int i = t; i < (LTILE + 12) * NF; i += NT) {
            int lr = i / NF;
            int ff = i - lr * NF;
            T[i] = xb[(size_t)clampi(l0 - 6 + lr) * NF + ff];
        }
    }
    __syncthreads();

    if (t < NF) {
        float m0[PERIOD];
        #pragma unroll
        for (int q = 0; q < PERIOD; ++q)
            m0[q] = dqmid(m0key[(size_t)(b * PERIOD + q) * KF + t]);
        float W0[PERIOD];
        {
            float s = 0.f;
            #pragma unroll
            for (int q = 0; q < 13; ++q) s += m0[q];
            W0[0] = s;
            #pragma unroll
            for (int q = 1; q < PERIOD; ++q)
                W0[q] = W0[q - 1] + m0[(q + 12) % 24] - m0[q - 1];
        }
        float lm[PERIOD];
        #pragma unroll
        for (int e = 0; e < 12; ++e) {
            int p = (e < 6) ? e : e + 12;
            lm[p] = medBedge[(size_t)(b * 12 + e) * KF + t];
        }
        #pragma unroll
        for (int p = 6; p < 18; ++p) lm[p] = m0[p] + W0[p - 6] * R13;
        float wt[PERIOD];
        {
            float s = 0.f;
            #pragma unroll
            for (int q = 0; q < 13; ++q) s += lm[q];
            wt[0] = s;
            #pragma unroll
            for (int q = 1; q < PERIOD; ++q)
                wt[q] = wt[q - 1] + lm[(q + 12) % 24] - lm[q - 1];
        }

        float s13 = 0.f;
        #pragma unroll
        for (int r = 0; r < 13; ++r) s13 += T[r * NF + t];

        const bool edgeLo = (kk == 0), edgeHi = (kk == NLT - 1);
        const size_t S = (size_t)NROWS * LROW;
        const size_t obase = (size_t)b * (LROW * NF) + (size_t)l0 * NF + (size_t)t;

        #pragma unroll
        for (int j = 0; j < LTILE; ++j) {
            float W = wt[(j + 18) % 24];
            if (edgeLo && j < 6) {
                float w = 0.f;
                #pragma unroll
                for (int jj = -6; jj <= 6; ++jj) { int m = j + jj; if (m < 0) m = 0; w += lm[m]; }
                W = w;
            }
            if (edgeHi && j >= 18) {
                float w = 0.f;
                #pragma unroll
                for (int jj = -6; jj <= 6; ++jj) { int m = j + jj; if (m > 23) m = 23; w += lm[m]; }
                W = w;
            }
            float tr = (s13 - W) * R13;
            float se = lm[j];
            float re = T[(j + 6) * NF + t] - tr - se;
            size_t o = obase + (size_t)(j * NF);
            __builtin_nontemporal_store(tr, &out[o]);
            __builtin_nontemporal_store(se, &out[S + o]);
            __builtin_nontemporal_store(re, &out[2 * S + o]);
            if (j < LTILE - 1)
                s13 += T[(j + 13) * NF + t] - T[j * NF + t];
        }
    }
}

extern "C" void kernel_launch(void* const* d_in, const int* in_sizes, int n_in,
                              void* d_out, int out_size, void* d_ws, size_t ws_size,
                              hipStream_t stream) {
    const float* x = (const float*)d_in[0];
    float* out = (float*)d_out;
    float* wsf = (float*)d_ws;
    (void)in_sizes; (void)n_in; (void)out_size; (void)ws_size;

    unsigned*       keys     = (unsigned*)wsf;
    unsigned short* m0key    = (unsigned short*)(wsf + 19489792);
    float*          medBedge = wsf + 19489792 + 159744;

    // DIAGNOSTIC: k_keys x16 and k_med0 x16 (others x1).
    // total - 337 = 15*(keys_body + med0_body); top-5 kernel identity + dur
    // pins the larger individually (and shows ITS counters); residual gives
    // the other. R18 strips reps and attacks the convicted kernel.
    hipLaunchKernelGGL(k_keys,   dim3(NB, NSLOT), dim3(NT), 0, stream, x, keys, 16);
    hipLaunchKernelGGL(k_med0,   dim3(NB * PERIOD), dim3(NT), 0, stream, keys, m0key, 16);
    hipLaunchKernelGGL(k_edge2,  dim3(NB * 12), dim3(NT), 0, stream, keys, m0key, medBedge);
    hipLaunchKernelGGL(stl_outputs, dim3(K2GRID), dim3(NT), 0, stream,
                       x, m0key, medBedge, out);
}

// Round 18
// 335.159 us; speedup vs baseline: 5.9056x; 5.9056x over previous
//
#include <hip/hip_runtime.h>

#define LROW    2904
#define PERIOD  24
#define CYC     121          // cycles; odd -> median = 0-indexed rank 60
#define NF      207
#define KF      208          // padded f-width (832B rows, 64B-aligned)
#define NB      64
#define NROWS   13248
#define NSLOT   61           // 121 keys packed 2/u32 (+1 sentinel halfword)
#define NT      256
#define LTILE   24
#define NLT     121
#define K2GRID  (NB * NLT)   // 7744
#define K2CHUNK (K2GRID / 8)
#define R13     (1.f / 13.f)

typedef unsigned short us2 __attribute__((ext_vector_type(2)));

__device__ __forceinline__ int clampi(int i) {
    return i < 0 ? 0 : (i >= LROW ? LROW - 1 : i);
}
// 16-bit fixed-point key: grid 2^-12, range [-8,8). Monotone (trunc+clamp).
__device__ __forceinline__ unsigned quantk(float d) {
    int ki = (int)fmaf(d, 4096.f, 32768.f);
    ki = ki < 0 ? 0 : (ki > 65535 ? 65535 : ki);
    return (unsigned)ki;
}
__device__ __forceinline__ float dqmid(unsigned k) {
    return ((float)(int)k - 32767.5f) * (1.f / 4096.f);
}

// Split-K rank select: lane pair (xor 1) shares one f; this lane holds 31 of
// the 61 packed slots (half0: 0..29 + zeroed K[30]; half1: 30..60). 31 u32
// fit in registers (~50 VGPR total) -- R17 showed K[61] at VGPR=36 forced
// 16x re-load of all slots. Counts combined per round via one shfl_xor.
// Largest T with cnt_ge(T) >= thr; thr=62 -> v[60], 61 -> v[61], 63 -> v[59].
__device__ __forceinline__ unsigned selN_split(const unsigned (&K)[31], int thr) {
    unsigned T = 0;
    const us2 one2 = __builtin_bit_cast(us2, 0x00010001u);
    for (int bit = 15; bit >= 0; --bit) {
        unsigned Tp = T | (1u << bit);
        unsigned tm32 = (Tp - 1u) | ((Tp - 1u) << 16);
        us2 tm2 = __builtin_bit_cast(us2, tm32);
        us2 acc = __builtin_bit_cast(us2, 0u);
        #pragma unroll
        for (int s = 0; s < 31; ++s) {
            us2 kv = __builtin_bit_cast(us2, K[s]);
            us2 dd = __builtin_elementwise_sub_sat(kv, tm2);  // max(0,k-(Tp-1))
            us2 mm = __builtin_elementwise_min(dd, one2);     // 1 iff k >= Tp
            acc = acc + mm;
        }
        unsigned a = __builtin_bit_cast(unsigned, acc);
        int cnt = (int)(a & 0xFFFFu) + (int)(a >> 16);
        cnt += __shfl_xor(cnt, 1);                            // pair total
        if (cnt >= thr) T = Tp;
    }
    return T;
}

// ===== K0: keys via contiguous float2 tile; nontemporal full-line stores ===
__global__ __launch_bounds__(256) void k_keys(const float* __restrict__ x,
                                              unsigned* __restrict__ keys) {
    __shared__ float T[62 * NF];           // rows l0-8 .. l0+53
    const int b  = blockIdx.x;
    const int cp = blockIdx.y;             // c-pair (2cp,2cp+1); cp=60: c=120
    const int fl = threadIdx.x;
    const int fe = fl < NF ? fl : NF - 1;
    const int l0 = cp * 48;
    const float* xb = x + (size_t)b * (LROW * NF);
    unsigned* kb = keys + ((size_t)b * PERIOD * NSLOT + cp) * KF + fl;

    if (cp != 0 && cp != 60) {
        const float2* s2 = (const float2*)(xb + (size_t)(l0 - 8) * NF);
        float2* t2 = (float2*)T;
        for (int i = fl; i < 62 * NF / 2; i += NT) t2[i] = s2[i];
    } else {
        for (int i = fl; i < 62 * NF; i += NT) {
            int lr = i / NF, ff = i - lr * NF;
            T[i] = xb[(size_t)clampi(l0 - 8 + lr) * NF + ff];
        }
    }
    __syncthreads();

    float r[13];
    #pragma unroll
    for (int i = 0; i < 13; ++i) r[i] = T[(i + 1) * NF + fe];
    float sum = ((r[0]+r[1])+(r[2]+r[3]))+((r[4]+r[5])+(r[6]+r[7]))
              + ((r[8]+r[9])+(r[10]+r[11])) + r[12];

    if (cp < 60) {
        unsigned pend[PERIOD];
        #pragma unroll
        for (int j = 0; j < 48; ++j) {
            float xn = T[(j + 14) * NF + fe];
            sum += xn - r[0];
            unsigned k = quantk(r[7] - sum * R13);
            if (j < 24) pend[j] = k;
            else if (fl < KF)
                __builtin_nontemporal_store(pend[j - 24] | (k << 16),
                                            &kb[(size_t)(j - 24) * (NSLOT * KF)]);
            #pragma unroll
            for (int i = 0; i < 12; ++i) r[i] = r[i + 1];
            r[12] = xn;
        }
    } else {
        #pragma unroll
        for (int j = 0; j < 24; ++j) {
            float xn = T[(j + 14) * NF + fe];
            sum += xn - r[0];
            unsigned k = quantk(r[7] - sum * R13);
            if (fl < KF)
                __builtin_nontemporal_store(k | 0xFFFF0000u,
                                            &kb[(size_t)j * (NSLOT * KF)]);
            #pragma unroll
            for (int i = 0; i < 12; ++i) r[i] = r[i + 1];
            r[12] = xn;
        }
    }
}

// ===== K1: iter-0 medians, split-K (2 lanes per f) =========================
__global__ __launch_bounds__(256) void k_med0(const unsigned* __restrict__ keys,
                                              unsigned short* __restrict__ m0key) {
    const int d  = blockIdx.x;                      // 1536 = 8*192, bijective
    const int bp = (d & 7) * 192 + (d >> 3);
    const int fb = blockIdx.y;                      // f-half: 0 or 1
    const int t  = threadIdx.x;
    const int f  = fb * 128 + (t >> 1);
    const int half = t & 1;
    const int fx = f < KF ? f : KF - 1;

    const unsigned* kp = keys + (size_t)bp * (NSLOT * KF) + fx
                       + (half ? (size_t)30 * KF : 0);
    unsigned K[31];
    #pragma unroll
    for (int s = 0; s < 31; ++s) K[s] = kp[(size_t)s * KF];
    if (!half) K[30] = 0;                           // slot 30 owned by half1

    unsigned T = selN_split(K, 62);
    if (!half && f < KF) m0key[(size_t)bp * KF + f] = (unsigned short)T;
}

// ===== K2: iter-1 edge resolve, O(1) replacement rule, split-K =============
__global__ __launch_bounds__(256) void k_edge2(const unsigned* __restrict__ keys,
                                               const unsigned short* __restrict__ m0key,
                                               float* __restrict__ medBedge) {
    const int d  = blockIdx.x;                      // 768 = 8*96, bijective
    const int be = (d & 7) * 96 + (d >> 3);
    const int b = be / 12, e = be - 12 * b;
    const int p = (e < 6) ? e : e + 12;
    const int fb = blockIdx.y;
    const int t  = threadIdx.x;
    const int f  = fb * 128 + (t >> 1);
    const int half = t & 1;
    const int fx = f < KF ? f : KF - 1;

    float m0[PERIOD];
    #pragma unroll
    for (int q = 0; q < PERIOD; ++q)
        m0[q] = dqmid(m0key[(size_t)(b * PERIOD + q) * KF + fx]);

    // static-index sums via 12-way uniform branch (rule #20)
    float wph = 0.f, we = 0.f;
    #pragma unroll
    for (int ee = 0; ee < 12; ++ee) if (ee == e) {
        const int pp = (ee < 6) ? ee : ee + 12;
        #pragma unroll
        for (int q = 0; q < 13; ++q) wph += m0[(pp + 18 + q) % 24];
        #pragma unroll
        for (int q = -6; q <= 6; ++q) {
            int aa = pp + q; if (aa < 0) aa = 0; if (aa > 23) aa = 23;
            we += m0[aa];
        }
    }

    const unsigned* kp = keys + (size_t)(b * PERIOD + p) * (NSLOT * KF) + fx
                       + (half ? (size_t)30 * KF : 0);
    unsigned K[31];
    #pragma unroll
    for (int s = 0; s < 31; ++s) K[s] = kp[(size_t)s * KF];
    if (!half) K[30] = 0;

    unsigned m = (unsigned)m0key[(size_t)(b * PERIOD + p) * KF + fx];
    // edge element (c=0 -> slot 0 low half; c=120 -> slot 60 low half)
    unsigned xk = keys[(size_t)(b * PERIOD + p) * (NSLOT * KF)
                       + (size_t)(p < 6 ? 0 : 60) * KF + fx] & 0xFFFFu;
    unsigned y = quantk(dqmid(xk) + (we - wph) * R13);

    int thr = (y > m) ? 61 : 63;                    // old-set v[61] or v[59]
    unsigned v = selN_split(K, thr);                // UNPATCHED set (rule)
    bool up = (y > m) && (xk <= m);
    bool dn = (y < m) && (xk >= m);
    unsigned nm = up ? (y < v ? y : v) : (dn ? (y > v ? y : v) : m);
    if (!half && f < KF)
        medBedge[(size_t)(b * 12 + e) * KF + f] = dqmid(nm) + wph * R13;
}

// ===== K3: outputs; reconstructs mB/W1 in-block (unchanged from R16) =======
__global__ __launch_bounds__(NT, 5) void stl_outputs(const float* __restrict__ x,
                                                     const unsigned short* __restrict__ m0key,
                                                     const float* __restrict__ medBedge,
                                                     float* __restrict__ out) {
    __shared__ float T[(LTILE + 12) * NF];

    const int d   = blockIdx.x;
    const int blk = (d & 7) * K2CHUNK + (d >> 3);
    const int b  = blk / NLT;
    const int kk = blk - b * NLT;
    const int l0 = kk * LTILE;
    const int t  = threadIdx.x;
    const float* xb = x + (size_t)b * (LROW * NF);

    if (kk != 0 && kk != NLT - 1) {
        const float2* s2 = (const float2*)(xb + (size_t)(l0 - 6) * NF);
        float2* t2 = (float2*)T;
        for (int i = t; i < (LTILE + 12) * NF / 2; i += NT) t2[i] = s2[i];
    } else {
        for (int i = t; i < (LTILE + 12) * NF; i += NT) {
            int lr = i / NF;
            int ff = i - lr * NF;
            T[i] = xb[(size_t)clampi(l0 - 6 + lr) * NF + ff];
        }
    }
    __syncthreads();

    if (t < NF) {
        float m0[PERIOD];
        #pragma unroll
        for (int q = 0; q < PERIOD; ++q)
            m0[q] = dqmid(m0key[(size_t)(b * PERIOD + q) * KF + t]);
        float W0[PERIOD];
        {
            float s = 0.f;
            #pragma unroll
            for (int q = 0; q < 13; ++q) s += m0[q];
            W0[0] = s;
            #pragma unroll
            for (int q = 1; q < PERIOD; ++q)
                W0[q] = W0[q - 1] + m0[(q + 12) % 24] - m0[q - 1];
        }
        float lm[PERIOD];
        #pragma unroll
        for (int e = 0; e < 12; ++e) {
            int p = (e < 6) ? e : e + 12;
            lm[p] = medBedge[(size_t)(b * 12 + e) * KF + t];
        }
        #pragma unroll
        for (int p = 6; p < 18; ++p) lm[p] = m0[p] + W0[p - 6] * R13;
        float wt[PERIOD];
        {
            float s = 0.f;
            #pragma unroll
            for (int q = 0; q < 13; ++q) s += lm[q];
            wt[0] = s;
            #pragma unroll
            for (int q = 1; q < PERIOD; ++q)
                wt[q] = wt[q - 1] + lm[(q + 12) % 24] - lm[q - 1];
        }

        float s13 = 0.f;
        #pragma unroll
        for (int r = 0; r < 13; ++r) s13 += T[r * NF + t];

        const bool edgeLo = (kk == 0), edgeHi = (kk == NLT - 1);
        const size_t S = (size_t)NROWS * LROW;
        const size_t obase = (size_t)b * (LROW * NF) + (size_t)l0 * NF + (size_t)t;

        #pragma unroll
        for (int j = 0; j < LTILE; ++j) {
            float W = wt[(j + 18) % 24];
            if (edgeLo && j < 6) {
                float w = 0.f;
                #pragma unroll
                for (int jj = -6; jj <= 6; ++jj) { int m = j + jj; if (m < 0) m = 0; w += lm[m]; }
                W = w;
            }
            if (edgeHi && j >= 18) {
                float w = 0.f;
                #pragma unroll
                for (int jj = -6; jj <= 6; ++jj) { int m = j + jj; if (m > 23) m = 23; w += lm[m]; }
                W = w;
            }
            float tr = (s13 - W) * R13;
            float se = lm[j];
            float re = T[(j + 6) * NF + t] - tr - se;
            size_t o = obase + (size_t)(j * NF);
            __builtin_nontemporal_store(tr, &out[o]);
            __builtin_nontemporal_store(se, &out[S + o]);
            __builtin_nontemporal_store(re, &out[2 * S + o]);
            if (j < LTILE - 1)
                s13 += T[(j + 13) * NF + t] - T[j * NF + t];
        }
    }
}

extern "C" void kernel_launch(void* const* d_in, const int* in_sizes, int n_in,
                              void* d_out, int out_size, void* d_ws, size_t ws_size,
                              hipStream_t stream) {
    const float* x = (const float*)d_in[0];
    float* out = (float*)d_out;
    float* wsf = (float*)d_ws;
    (void)in_sizes; (void)n_in; (void)out_size; (void)ws_size;

    // workspace (floats): [keys 1536*61*208 = 19489792 u32]
    //                     [m0key 1536*208 ushort = 159744 fl]
    //                     [medBedge 64*12*208 = 159744 fl]   total ~79.2 MB
    unsigned*       keys     = (unsigned*)wsf;
    unsigned short* m0key    = (unsigned short*)(wsf + 19489792);
    float*          medBedge = wsf + 19489792 + 159744;

    hipLaunchKernelGGL(k_keys,   dim3(NB, NSLOT), dim3(NT), 0, stream, x, keys);
    hipLaunchKernelGGL(k_med0,   dim3(NB * PERIOD, 2), dim3(NT), 0, stream, keys, m0key);
    hipLaunchKernelGGL(k_edge2,  dim3(NB * 12, 2), dim3(NT), 0, stream, keys, m0key, medBedge);
    hipLaunchKernelGGL(stl_outputs, dim3(K2GRID), dim3(NT), 0, stream,
                       x, m0key, medBedge, out);
}